// Round 17
// baseline (96.612 us; speedup 1.0000x reference)
//
#include <hip/hip_runtime.h>
#include <hip/hip_bf16.h>

typedef int   i32x4  __attribute__((ext_vector_type(4)));
typedef int   i32x8  __attribute__((ext_vector_type(8)));
typedef float f32x16 __attribute__((ext_vector_type(16)));

#define GLL16(gp, lp)                                                          \
  __builtin_amdgcn_global_load_lds(                                            \
      (const __attribute__((address_space(1))) void*)(gp),                     \
      (__attribute__((address_space(3))) void*)(lp), 16, 0, 0)

namespace {
constexpr int NB = 4, CINc = 256, Hc = 56, Wc = 56, COUTc = 256;
constexpr int LSP = 56 * 56;           // 3136 output pixels per image
constexpr int MD  = NB * LSP;          // 12544 GEMM rows
constexpr int KT  = 2304;              // 256*9 (K elements)
constexpr int YP = 58, XP = 58;        // padded spatial

constexpr size_t OFF_A0 = 8192;        // slot_a@0, slot0@2048, slot1@4096, slot_v@6144
constexpr size_t SZ_A4  = (size_t)NB * YP * XP * 128;       // 1,722,368
constexpr size_t OFF_A1 = OFF_A0 + SZ_A4;
constexpr size_t OFF_BW = OFF_A1 + SZ_A4;
constexpr size_t SZ_BW4 = (size_t)COUTc * (KT / 2);         // 294,912
constexpr size_t OFF_P0 = OFF_BW + SZ_BW4;
constexpr size_t SZ_P   = (size_t)MD * COUTc * 2;           // 6,422,528 (i16)
constexpr size_t OFF_P1 = OFF_P0 + SZ_P;                    // end ~16.6 MB
} // namespace

__device__ __forceinline__ float wave_max_f(const float* __restrict__ s, int n) {
  float m = 0.f;
  for (int i = (threadIdx.x & 63); i < n; i += 64) m = fmaxf(m, s[i]);
#pragma unroll
  for (int off = 32; off; off >>= 1) m = fmaxf(m, __shfl_xor(m, off));
  return m;
}
__device__ __forceinline__ int wave_max_i(const int* __restrict__ s, int n) {
  int m = 0;
  for (int i = (threadIdx.x & 63); i < n; i += 64) m = max(m, s[i]);
#pragma unroll
  for (int off = 32; off; off >>= 1) m = max(m, __shfl_xor(m, off));
  return m;
}

// ============ K1: absmax(x) partials + binarize/pack W (fp4) ============
__global__ __launch_bounds__(256) void k_prep(const float* __restrict__ x,
                                              const float* __restrict__ w,
                                              char* __restrict__ ws) {
  __shared__ unsigned char sW[KT];     // fp4 codes: +1 -> 0x2, -1 -> 0xA
  __shared__ float redf[4];
  float* slot_a = (float*)ws;
  char* bw4 = ws + OFF_BW;
  const int tid = threadIdx.x, bid = blockIdx.x;
  const int gtid = bid * 256 + tid;

  {
    const float* src = w + (size_t)bid * KT;
    for (int t = tid; t < KT; t += 256)             // t = cin*9 + s
      sW[t] = src[t] >= 0.f ? 0x2u : 0xAu;
    __syncthreads();
    char4* dst4 = (char4*)(bw4 + (size_t)bid * (KT / 2));
    for (int j4 = tid; j4 < KT / 8; j4 += 256) {    // 288 char4 per co
      char4 v; unsigned char* vp = (unsigned char*)&v;
#pragma unroll
      for (int e = 0; e < 4; ++e) {
        int b = j4 * 4 + e;
        int cin = (2 * b) & 255, s = (2 * b) >> 8;
        vp[e] = (unsigned char)(sW[cin * 9 + s] | (sW[(cin + 1) * 9 + s] << 4));
      }
      dst4[j4] = v;
    }
  }
  {
    float mx = 0.f;
    const float4* x4 = (const float4*)x;
    const int n4 = NB * CINc * Hc * Wc / 4;         // 802,816
    for (int i = gtid; i < n4; i += 256 * 256) {
      float4 v = x4[i];
      mx = fmaxf(mx, fmaxf(fmaxf(fabsf(v.x), fabsf(v.y)), fmaxf(fabsf(v.z), fabsf(v.w))));
    }
#pragma unroll
    for (int off = 32; off; off >>= 1) mx = fmaxf(mx, __shfl_xor(mx, off));
    if ((tid & 63) == 0) redf[tid >> 6] = mx;
    __syncthreads();
    if (tid == 0) slot_a[bid] = fmaxf(fmaxf(redf[0], redf[1]), fmaxf(redf[2], redf[3]));
  }
}

// ============ K2: quantize -> fp4-code DAC slices + zero own pad borders ============
__global__ __launch_bounds__(1024) void k_quant(const float* __restrict__ x,
                                                char* __restrict__ ws) {
  __shared__ unsigned char t0[56 * 256];
  __shared__ unsigned char t1[56 * 256];
  const float* slot_a = (const float*)ws;
  char* a0 = ws + OFF_A0;
  char* a1 = ws + OFF_A1;
  const int n = blockIdx.x / Hc, h = blockIdx.x % Hc;
  const float gmax = wave_max_f(slot_a, 256);
  const float sx = fmaxf(__fdiv_rn(gmax, 7.0f), 1e-12f);

  {
    const int tid = threadIdx.x;
    if (tid < 16) {
      int cell = tid >> 3, seg = (tid & 7) * 16;
      int xx = cell ? 57 : 0;
      size_t base = (((size_t)n * YP + (h + 1)) * XP + xx) * 128 + seg;
      *(int4*)&a0[base] = int4{0, 0, 0, 0};
      *(int4*)&a1[base] = int4{0, 0, 0, 0};
    }
    if (h == 0 || h == 55) {
      int yy = (h == 0) ? 0 : 57;
      for (int i = tid; i < 464; i += 1024) {
        size_t base = ((size_t)n * YP + yy) * (size_t)XP * 128 + (size_t)i * 16;
        *(int4*)&a0[base] = int4{0, 0, 0, 0};
        *(int4*)&a1[base] = int4{0, 0, 0, 0};
      }
    }
  }

  const int c = threadIdx.x & 255, wq = threadIdx.x >> 8;
  const float2* src = (const float2*)(x + (((size_t)n * CINc + c) * Hc + h) * Wc + wq * 14);
#pragma unroll
  for (int j = 0; j < 7; ++j) {
    float2 v = src[j];
    float arr[2] = {v.x, v.y};
#pragma unroll
    for (int e = 0; e < 2; ++e) {
      float qf = rintf(__fdiv_rn(arr[e], sx));
      qf = fminf(7.f, fmaxf(-7.f, qf));
      int qi = (int)qf;
      int mag = qi < 0 ? -qi : qi;
      int m0_ = mag & 3, m1_ = mag >> 2;
      int c0 = (m0_ == 3 ? 5 : (m0_ << 1)) | ((qi < 0 && m0_) ? 8 : 0);
      int c1 = (m1_ ? 2 : 0) | ((qi < 0 && m1_) ? 8 : 0);
      int ww = wq * 14 + j * 2 + e;
      t0[ww * 256 + c] = (unsigned char)c0;
      t1[ww * 256 + c] = (unsigned char)c1;
    }
  }
  __syncthreads();
  {
    int idx = threadIdx.x;              // 56 rows x 8 int4-chunks = 448 slots
    if (idx < 448) {
      int wr = idx >> 3, cs = (idx & 7) * 32;
      int4 o0, o1;
      unsigned char* b0 = (unsigned char*)&o0;
      unsigned char* b1 = (unsigned char*)&o1;
#pragma unroll
      for (int b = 0; b < 16; ++b) {
        b0[b] = (unsigned char)(t0[wr * 256 + cs + 2 * b] | (t0[wr * 256 + cs + 2 * b + 1] << 4));
        b1[b] = (unsigned char)(t1[wr * 256 + cs + 2 * b] | (t1[wr * 256 + cs + 2 * b + 1] << 4));
      }
      size_t dst = (((size_t)n * YP + (h + 1)) * XP + (wr + 1)) * 128 + (idx & 7) * 16;
      *(int4*)&a0[dst] = o0;
      *(int4*)&a1[dst] = o1;
    }
  }
}

// ============ K3: dual MX-fp4 GEMM, 128x64 tile, 392 blocks, counted-vmcnt ============
__global__ __launch_bounds__(512) void k_gemm(char* __restrict__ ws) {
  __shared__ __align__(16) char sA0[2 * 16384];
  __shared__ __align__(16) char sA1[2 * 16384];
  __shared__ __align__(16) char sB[2 * 8192];     // 80 KB -> 2 blocks/CU

  const char* a0cl = ws + OFF_A0;
  const char* a1cl = ws + OFF_A1;
  const char* bw4  = ws + OFF_BW;
  short* p0 = (short*)(ws + OFF_P0);
  short* p1 = (short*)(ws + OFF_P1);
  int* slot0 = (int*)(ws + 2048);
  int* slot1 = (int*)(ws + 4096);

  const int tid = threadIdx.x;
  const int lane = tid & 63, wid = tid >> 6;
  const int wm = wid >> 1, wn = wid & 1;

  const int bid = blockIdx.x;
  const int wg = (bid & 7) * 49 + (bid >> 3);     // 392 = 8*49 exact XCD swizzle
  const int mblk = wg % 98, nblk = wg / 98;
  const int m0 = mblk * 128, n0 = nblk * 64;

  f32x16 acc0 = {};
  f32x16 acc1 = {};

  const int trow = tid >> 3;
  const int cbs = (((tid & 7) << 4) ^ ((trow & 7) << 4));

  int rn[2], roh[2], rww[2];
#pragma unroll
  for (int p = 0; p < 2; ++p) {
    int m = m0 + p * 64 + trow;
    rn[p] = m / LSP; int l = m - rn[p] * LSP;
    roh[p] = l / 56; rww[p] = l - roh[p] * 56;
  }
  const int lbase0 = (wid * 8) * 128;
  const int lbase1 = (64 + wid * 8) * 128;
  const int lbaseB = wid * 8 * 128;

  auto STAGE = [&](int kb, int buf) {
    const int kh = kb / 3, kw = kb - kh * 3;
    {
      size_t ga = (((size_t)rn[0] * YP + (roh[0] + kh)) * XP + (rww[0] + kw)) * 128 + cbs;
      GLL16(a0cl + ga, sA0 + buf * 16384 + lbase0);
      GLL16(a1cl + ga, sA1 + buf * 16384 + lbase0);
    }
    {
      size_t ga = (((size_t)rn[1] * YP + (roh[1] + kh)) * XP + (rww[1] + kw)) * 128 + cbs;
      GLL16(a0cl + ga, sA0 + buf * 16384 + lbase1);
      GLL16(a1cl + ga, sA1 + buf * 16384 + lbase1);
    }
    {
      size_t gb = (size_t)(n0 + trow) * (KT / 2) + kb * 128 + cbs;
      GLL16(bw4 + gb, sB + buf * 8192 + lbaseB);
    }
  };

  const int arow = wm * 32 + (lane & 31);
  const int brow = wn * 32 + (lane & 31);
  const int kh16 = lane >> 5;

  auto COMPUTE = [&](int buf) {
    const char* bA0 = sA0 + buf * 16384 + arow * 128;
    const char* bA1 = sA1 + buf * 16384 + arow * 128;
    const char* bB  = sB + buf * 8192 + brow * 128;
#pragma unroll
    for (int c = 0; c < 4; ++c) {
      const int seg = c * 2 + kh16;
      i32x4 a0v = *(const i32x4*)(bA0 + ((seg ^ (arow & 7)) << 4));
      i32x4 a1v = *(const i32x4*)(bA1 + ((seg ^ (arow & 7)) << 4));
      i32x4 bv  = *(const i32x4*)(bB + ((seg ^ (brow & 7)) << 4));
      i32x8 a0e = {a0v[0], a0v[1], a0v[2], a0v[3], 0, 0, 0, 0};
      i32x8 a1e = {a1v[0], a1v[1], a1v[2], a1v[3], 0, 0, 0, 0};
      i32x8 be  = {bv[0], bv[1], bv[2], bv[3], 0, 0, 0, 0};
      acc0 = __builtin_amdgcn_mfma_scale_f32_32x32x64_f8f6f4(
          a0e, be, acc0, 4, 4, 0, 0x7F7F7F7F, 0, 0x7F7F7F7F);
      acc1 = __builtin_amdgcn_mfma_scale_f32_32x32x64_f8f6f4(
          a1e, be, acc1, 4, 4, 0, 0x7F7F7F7F, 0, 0x7F7F7F7F);
    }
  };

  STAGE(0, 0);
  STAGE(1, 1);

  int buf = 0;
#pragma unroll 1
  for (int kb = 0; kb < 9; ++kb) {
    if (kb < 8) {
      asm volatile("s_waitcnt vmcnt(5)" ::: "memory");
    } else {
      asm volatile("s_waitcnt vmcnt(0)" ::: "memory");
    }
    __builtin_amdgcn_s_barrier();
    asm volatile("" ::: "memory");
    COMPUTE(buf);
    asm volatile("" ::: "memory");
    __builtin_amdgcn_s_barrier();
    asm volatile("" ::: "memory");
    if (kb < 7) STAGE(kb + 2, buf);
    buf ^= 1;
  }

  int* red = (int*)sB;
  int mx0 = 0, mx1 = 0;
  {
    const int co = n0 + wn * 32 + (lane & 31);
    const int rbase = m0 + wm * 32 + 4 * (lane >> 5);
#pragma unroll
    for (int r = 0; r < 16; ++r) {
      const int m = rbase + (r & 3) + 8 * (r >> 2);
      int v0 = __float2int_rn(acc0[r]);
      int v1 = __float2int_rn(acc1[r]);
      mx0 = max(mx0, v0 < 0 ? -v0 : v0);
      mx1 = max(mx1, v1 < 0 ? -v1 : v1);
      size_t idx = (size_t)m * COUTc + co;
      p0[idx] = (short)v0;
      p1[idx] = (short)v1;
    }
  }
#pragma unroll
  for (int off = 32; off; off >>= 1) {
    mx0 = max(mx0, __shfl_xor(mx0, off));
    mx1 = max(mx1, __shfl_xor(mx1, off));
  }
  if (lane == 0) { red[wid] = mx0; red[wid + 8] = mx1; }
  __syncthreads();
  if (tid == 0) {
    int a = 0, b = 0;
#pragma unroll
    for (int i = 0; i < 8; ++i) { a = max(a, red[i]); b = max(b, red[i + 8]); }
    slot0[bid] = a;
    slot1[bid] = b;
  }
}

__device__ __forceinline__ float compute_val(int a, int b, float sa0, float sa1) {
  float q0 = rintf(__fdiv_rn((float)a, sa0));
  q0 = fminf(31.f, fmaxf(-31.f, q0));
  float q1 = rintf(__fdiv_rn((float)b, sa1));
  q1 = fminf(31.f, fmaxf(-31.f, q1));
  float acc = __fadd_rn(__fmul_rn(q0, sa0), __fmul_rn(__fmul_rn(q1, sa1), 4.0f));
  float pe = (float)(a + 4 * b);
  return __fadd_rn(pe, __fsub_rn(acc, pe));
}

// ============ K4: max|val| partials ============
__global__ __launch_bounds__(256) void k_maxval(char* __restrict__ ws) {
  __shared__ float redf[4];
  const short* p0 = (const short*)(ws + OFF_P0);
  const short* p1 = (const short*)(ws + OFF_P1);
  const int* slot0 = (const int*)(ws + 2048);
  const int* slot1 = (const int*)(ws + 4096);
  float* slot_v = (float*)(ws + 6144);

  const float sa0 = fmaxf(__fdiv_rn((float)wave_max_i(slot0, 392), 31.0f), 1e-12f);
  const float sa1 = fmaxf(__fdiv_rn((float)wave_max_i(slot1, 392), 31.0f), 1e-12f);

  float mv = 0.f;
  const short4* p04 = (const short4*)p0;
  const short4* p14 = (const short4*)p1;
  const int n4 = MD * COUTc / 4;
  for (int i = blockIdx.x * 256 + threadIdx.x; i < n4; i += 512 * 256) {
    short4 a = p04[i], b = p14[i];
    mv = fmaxf(mv, fmaxf(fmaxf(fabsf(compute_val(a.x, b.x, sa0, sa1)),
                               fabsf(compute_val(a.y, b.y, sa0, sa1))),
                         fmaxf(fabsf(compute_val(a.z, b.z, sa0, sa1)),
                               fabsf(compute_val(a.w, b.w, sa0, sa1)))));
  }
#pragma unroll
  for (int off = 32; off; off >>= 1) mv = fmaxf(mv, __shfl_xor(mv, off));
  if ((threadIdx.x & 63) == 0) redf[threadIdx.x >> 6] = mv;
  __syncthreads();
  if (threadIdx.x == 0)
    slot_v[blockIdx.x] = fmaxf(fmaxf(redf[0], redf[1]), fmaxf(redf[2], redf[3]));
}

// ============ K5: requant + bias + transpose to [n][co][l] ============
__global__ __launch_bounds__(256) void k_final(const float* __restrict__ bias,
                                               float* __restrict__ out,
                                               char* __restrict__ ws) {
  __shared__ short t0[64 * 66];
  __shared__ short t1[64 * 66];
  const short* p0 = (const short*)(ws + OFF_P0);
  const short* p1 = (const short*)(ws + OFF_P1);
  const float* slot_a = (const float*)ws;
  const int* slot0 = (const int*)(ws + 2048);
  const int* slot1 = (const int*)(ws + 4096);
  const float* slot_v = (const float*)(ws + 6144);

  const float sx  = fmaxf(__fdiv_rn(wave_max_f(slot_a, 256), 7.0f), 1e-12f);
  const float sa0 = fmaxf(__fdiv_rn((float)wave_max_i(slot0, 392), 31.0f), 1e-12f);
  const float sa1 = fmaxf(__fdiv_rn((float)wave_max_i(slot1, 392), 31.0f), 1e-12f);
  const float so  = fmaxf(__fdiv_rn(__fmul_rn(wave_max_f(slot_v, 512), sx), 127.0f), 1e-12f);

  const int m0 = blockIdx.x * 64, co0 = blockIdx.y * 64;
  const int trow = threadIdx.x >> 3, tseg = threadIdx.x & 7;
#pragma unroll
  for (int p = 0; p < 2; ++p) {
    int ml = p * 32 + trow;
    int4 v0 = *(const int4*)&p0[(size_t)(m0 + ml) * COUTc + co0 + tseg * 8];
    int4 v1 = *(const int4*)&p1[(size_t)(m0 + ml) * COUTc + co0 + tseg * 8];
    const short* s0 = (const short*)&v0;
    const short* s1 = (const short*)&v1;
#pragma unroll
    for (int j = 0; j < 8; ++j) {
      int col = tseg * 8 + j;
      t0[col * 66 + ml] = s0[j];
      t1[col * 66 + ml] = s1[j];
    }
  }
  __syncthreads();
  const int lane16 = threadIdx.x & 15, cg = threadIdx.x >> 4;
#pragma unroll
  for (int p = 0; p < 4; ++p) {
    int col = p * 16 + cg;
    int m4 = lane16 * 4;
    int mg = m0 + m4;
    int nimg = mg / LSP;
    int l = mg - nimg * LSP;
    int co = co0 + col;
    float bv = bias[co];
    float4 o;
    float* op = &o.x;
#pragma unroll
    for (int e = 0; e < 4; ++e) {
      float val = compute_val(t0[col * 66 + m4 + e], t1[col * 66 + m4 + e], sa0, sa1);
      float u = __fmul_rn(val, sx);
      float r = rintf(__fdiv_rn(u, so));
      r = fminf(127.f, fmaxf(-127.f, r));
      op[e] = __fadd_rn(__fmul_rn(r, so), bv);
    }
    *(float4*)&out[((size_t)nimg * COUTc + co) * LSP + l] = o;
  }
}

extern "C" void kernel_launch(void* const* d_in, const int* in_sizes, int n_in,
                              void* d_out, int out_size, void* d_ws, size_t ws_size,
                              hipStream_t stream) {
  const float* x    = (const float*)d_in[0];
  const float* w    = (const float*)d_in[1];
  const float* bias = (const float*)d_in[2];
  float* out = (float*)d_out;
  char* ws = (char*)d_ws;

  // MEASUREMENT ROUND: duplicate the four non-GEMM kernels (all idempotent).
  // dT vs r16's 64.45 us = their summed marginal cost.
  k_prep<<<256, 256, 0, stream>>>(x, w, ws);
  k_prep<<<256, 256, 0, stream>>>(x, w, ws);
  k_quant<<<NB * Hc, 1024, 0, stream>>>(x, ws);
  k_quant<<<NB * Hc, 1024, 0, stream>>>(x, ws);
  k_gemm<<<392, 512, 0, stream>>>(ws);
  k_maxval<<<512, 256, 0, stream>>>(ws);
  k_maxval<<<512, 256, 0, stream>>>(ws);
  k_final<<<dim3(MD / 64, COUTc / 64), 256, 0, stream>>>(bias, out, ws);
  k_final<<<dim3(MD / 64, COUTc / 64), 256, 0, stream>>>(bias, out, ws);
}

// Round 18
// 64.182 us; speedup vs baseline: 1.5053x; 1.5053x over previous
//
#include <hip/hip_runtime.h>
#include <hip/hip_bf16.h>

typedef int   i32x4  __attribute__((ext_vector_type(4)));
typedef int   i32x8  __attribute__((ext_vector_type(8)));
typedef float f32x16 __attribute__((ext_vector_type(16)));

#define GLL16(gp, lp)                                                          \
  __builtin_amdgcn_global_load_lds(                                            \
      (const __attribute__((address_space(1))) void*)(gp),                     \
      (__attribute__((address_space(3))) void*)(lp), 16, 0, 0)

namespace {
constexpr int NB = 4, CINc = 256, Hc = 56, Wc = 56, COUTc = 256;
constexpr int LSP = 56 * 56;           // 3136 output pixels per image
constexpr int MD  = NB * LSP;          // 12544 GEMM rows
constexpr int KT  = 2304;              // 256*9 (K elements)
constexpr int YP = 58, XP = 58;        // padded spatial

constexpr size_t OFF_A0 = 8192;        // slot_a@0, slot0@2048, slot1@4096, slot_v@6144
constexpr size_t SZ_A4  = (size_t)NB * YP * XP * 128;       // 1,722,368
constexpr size_t OFF_A1 = OFF_A0 + SZ_A4;
constexpr size_t OFF_BW = OFF_A1 + SZ_A4;
constexpr size_t SZ_BW4 = (size_t)COUTc * (KT / 2);         // 294,912
constexpr size_t OFF_P0 = OFF_BW + SZ_BW4;
constexpr size_t SZ_P   = (size_t)MD * COUTc * 2;           // 6,422,528 (i16)
constexpr size_t OFF_P1 = OFF_P0 + SZ_P;                    // end ~16.6 MB
} // namespace

__device__ __forceinline__ float wave_max_f(const float* __restrict__ s, int n) {
  float m = 0.f;
  for (int i = (threadIdx.x & 63); i < n; i += 64) m = fmaxf(m, s[i]);
#pragma unroll
  for (int off = 32; off; off >>= 1) m = fmaxf(m, __shfl_xor(m, off));
  return m;
}
__device__ __forceinline__ int wave_max_i(const int* __restrict__ s, int n) {
  int m = 0;
  for (int i = (threadIdx.x & 63); i < n; i += 64) m = max(m, s[i]);
#pragma unroll
  for (int off = 32; off; off >>= 1) m = max(m, __shfl_xor(m, off));
  return m;
}

// ============ K1: absmax(x) partials + binarize/pack W (fp4) ============
__global__ __launch_bounds__(256) void k_prep(const float* __restrict__ x,
                                              const float* __restrict__ w,
                                              char* __restrict__ ws) {
  __shared__ unsigned char sW[KT];     // fp4 codes: +1 -> 0x2, -1 -> 0xA
  __shared__ float redf[4];
  float* slot_a = (float*)ws;
  char* bw4 = ws + OFF_BW;
  const int tid = threadIdx.x, bid = blockIdx.x;
  const int gtid = bid * 256 + tid;

  {
    const float* src = w + (size_t)bid * KT;
    for (int t = tid; t < KT; t += 256)             // t = cin*9 + s
      sW[t] = src[t] >= 0.f ? 0x2u : 0xAu;
    __syncthreads();
    char4* dst4 = (char4*)(bw4 + (size_t)bid * (KT / 2));
    for (int j4 = tid; j4 < KT / 8; j4 += 256) {    // 288 char4 per co
      char4 v; unsigned char* vp = (unsigned char*)&v;
#pragma unroll
      for (int e = 0; e < 4; ++e) {
        int b = j4 * 4 + e;
        int cin = (2 * b) & 255, s = (2 * b) >> 8;
        vp[e] = (unsigned char)(sW[cin * 9 + s] | (sW[(cin + 1) * 9 + s] << 4));
      }
      dst4[j4] = v;
    }
  }
  {
    float mx = 0.f;
    const float4* x4 = (const float4*)x;
    const int n4 = NB * CINc * Hc * Wc / 4;         // 802,816
    for (int i = gtid; i < n4; i += 256 * 256) {
      float4 v = x4[i];
      mx = fmaxf(mx, fmaxf(fmaxf(fabsf(v.x), fabsf(v.y)), fmaxf(fabsf(v.z), fabsf(v.w))));
    }
#pragma unroll
    for (int off = 32; off; off >>= 1) mx = fmaxf(mx, __shfl_xor(mx, off));
    if ((tid & 63) == 0) redf[tid >> 6] = mx;
    __syncthreads();
    if (tid == 0) slot_a[bid] = fmaxf(fmaxf(redf[0], redf[1]), fmaxf(redf[2], redf[3]));
  }
}

// ============ K2: quantize -> fp4-code DAC slices + zero own pad borders ============
// COALESCED reads: c = tid>>2, q = tid&3 -> lanes 0-3 cover one 64B line (float4 each).
// j coverage per q: {q, q+4, q+8, q+12} ∩ [0,14) -> union over q = 0..13 exactly once.
__global__ __launch_bounds__(1024) void k_quant(const float* __restrict__ x,
                                                char* __restrict__ ws) {
  __shared__ unsigned char t0[56 * 256];
  __shared__ unsigned char t1[56 * 256];
  const float* slot_a = (const float*)ws;
  char* a0 = ws + OFF_A0;
  char* a1 = ws + OFF_A1;
  const int n = blockIdx.x / Hc, h = blockIdx.x % Hc;
  const float gmax = wave_max_f(slot_a, 256);
  const float sx = fmaxf(__fdiv_rn(gmax, 7.0f), 1e-12f);

  // ---- border zeroing (disjoint from interior writes; no sync needed) ----
  {
    const int tid = threadIdx.x;
    if (tid < 16) {
      int cell = tid >> 3, seg = (tid & 7) * 16;
      int xx = cell ? 57 : 0;
      size_t base = (((size_t)n * YP + (h + 1)) * XP + xx) * 128 + seg;
      *(int4*)&a0[base] = int4{0, 0, 0, 0};
      *(int4*)&a1[base] = int4{0, 0, 0, 0};
    }
    if (h == 0 || h == 55) {
      int yy = (h == 0) ? 0 : 57;
      for (int i = tid; i < 464; i += 1024) {
        size_t base = ((size_t)n * YP + yy) * (size_t)XP * 128 + (size_t)i * 16;
        *(int4*)&a0[base] = int4{0, 0, 0, 0};
        *(int4*)&a1[base] = int4{0, 0, 0, 0};
      }
    }
  }

  const int c = threadIdx.x >> 2, q = threadIdx.x & 3;
  const float4* src4 = (const float4*)(x + (((size_t)n * CINc + c) * Hc + h) * Wc);
#pragma unroll 1
  for (int j = q; j < 14; j += 4) {                 // 14 float4 per (n,c,h) row
    float4 v = src4[j];
    float arr[4] = {v.x, v.y, v.z, v.w};
#pragma unroll
    for (int e = 0; e < 4; ++e) {
      float qf = rintf(__fdiv_rn(arr[e], sx));
      qf = fminf(7.f, fmaxf(-7.f, qf));
      int qi = (int)qf;
      int mag = qi < 0 ? -qi : qi;
      int m0_ = mag & 3, m1_ = mag >> 2;
      // fp4 E2M1 codes: 0->0x0, 1->0x2, 2->0x4, 3->0x5; sign bit 0x8
      int c0 = (m0_ == 3 ? 5 : (m0_ << 1)) | ((qi < 0 && m0_) ? 8 : 0);
      int c1 = (m1_ ? 2 : 0) | ((qi < 0 && m1_) ? 8 : 0);
      int ww = j * 4 + e;
      t0[ww * 256 + c] = (unsigned char)c0;
      t1[ww * 256 + c] = (unsigned char)c1;
    }
  }
  __syncthreads();
  {
    int idx = threadIdx.x;              // 56 rows x 8 int4-chunks = 448 slots
    if (idx < 448) {
      int wr = idx >> 3, cs = (idx & 7) * 32;
      int4 o0, o1;
      unsigned char* b0 = (unsigned char*)&o0;
      unsigned char* b1 = (unsigned char*)&o1;
#pragma unroll
      for (int b = 0; b < 16; ++b) {
        b0[b] = (unsigned char)(t0[wr * 256 + cs + 2 * b] | (t0[wr * 256 + cs + 2 * b + 1] << 4));
        b1[b] = (unsigned char)(t1[wr * 256 + cs + 2 * b] | (t1[wr * 256 + cs + 2 * b + 1] << 4));
      }
      size_t dst = (((size_t)n * YP + (h + 1)) * XP + (wr + 1)) * 128 + (idx & 7) * 16;
      *(int4*)&a0[dst] = o0;
      *(int4*)&a1[dst] = o1;
    }
  }
}

// ============ K3: dual MX-fp4 GEMM, 128x64 tile, 392 blocks, counted-vmcnt ============
__global__ __launch_bounds__(512) void k_gemm(char* __restrict__ ws) {
  __shared__ __align__(16) char sA0[2 * 16384];
  __shared__ __align__(16) char sA1[2 * 16384];
  __shared__ __align__(16) char sB[2 * 8192];     // 80 KB -> 2 blocks/CU

  const char* a0cl = ws + OFF_A0;
  const char* a1cl = ws + OFF_A1;
  const char* bw4  = ws + OFF_BW;
  short* p0 = (short*)(ws + OFF_P0);
  short* p1 = (short*)(ws + OFF_P1);
  int* slot0 = (int*)(ws + 2048);
  int* slot1 = (int*)(ws + 4096);

  const int tid = threadIdx.x;
  const int lane = tid & 63, wid = tid >> 6;
  const int wm = wid >> 1, wn = wid & 1;

  const int bid = blockIdx.x;
  const int wg = (bid & 7) * 49 + (bid >> 3);     // 392 = 8*49 exact XCD swizzle
  const int mblk = wg % 98, nblk = wg / 98;
  const int m0 = mblk * 128, n0 = nblk * 64;

  f32x16 acc0 = {};
  f32x16 acc1 = {};

  const int trow = tid >> 3;
  const int cbs = (((tid & 7) << 4) ^ ((trow & 7) << 4));

  int rn[2], roh[2], rww[2];
#pragma unroll
  for (int p = 0; p < 2; ++p) {
    int m = m0 + p * 64 + trow;
    rn[p] = m / LSP; int l = m - rn[p] * LSP;
    roh[p] = l / 56; rww[p] = l - roh[p] * 56;
  }
  const int lbase0 = (wid * 8) * 128;
  const int lbase1 = (64 + wid * 8) * 128;
  const int lbaseB = wid * 8 * 128;

  auto STAGE = [&](int kb, int buf) {
    const int kh = kb / 3, kw = kb - kh * 3;
    {
      size_t ga = (((size_t)rn[0] * YP + (roh[0] + kh)) * XP + (rww[0] + kw)) * 128 + cbs;
      GLL16(a0cl + ga, sA0 + buf * 16384 + lbase0);
      GLL16(a1cl + ga, sA1 + buf * 16384 + lbase0);
    }
    {
      size_t ga = (((size_t)rn[1] * YP + (roh[1] + kh)) * XP + (rww[1] + kw)) * 128 + cbs;
      GLL16(a0cl + ga, sA0 + buf * 16384 + lbase1);
      GLL16(a1cl + ga, sA1 + buf * 16384 + lbase1);
    }
    {
      size_t gb = (size_t)(n0 + trow) * (KT / 2) + kb * 128 + cbs;
      GLL16(bw4 + gb, sB + buf * 8192 + lbaseB);
    }
  };

  const int arow = wm * 32 + (lane & 31);
  const int brow = wn * 32 + (lane & 31);
  const int kh16 = lane >> 5;

  auto COMPUTE = [&](int buf) {
    const char* bA0 = sA0 + buf * 16384 + arow * 128;
    const char* bA1 = sA1 + buf * 16384 + arow * 128;
    const char* bB  = sB + buf * 8192 + brow * 128;
#pragma unroll
    for (int c = 0; c < 4; ++c) {
      const int seg = c * 2 + kh16;
      i32x4 a0v = *(const i32x4*)(bA0 + ((seg ^ (arow & 7)) << 4));
      i32x4 a1v = *(const i32x4*)(bA1 + ((seg ^ (arow & 7)) << 4));
      i32x4 bv  = *(const i32x4*)(bB + ((seg ^ (brow & 7)) << 4));
      i32x8 a0e = {a0v[0], a0v[1], a0v[2], a0v[3], 0, 0, 0, 0};
      i32x8 a1e = {a1v[0], a1v[1], a1v[2], a1v[3], 0, 0, 0, 0};
      i32x8 be  = {bv[0], bv[1], bv[2], bv[3], 0, 0, 0, 0};
      acc0 = __builtin_amdgcn_mfma_scale_f32_32x32x64_f8f6f4(
          a0e, be, acc0, 4, 4, 0, 0x7F7F7F7F, 0, 0x7F7F7F7F);
      acc1 = __builtin_amdgcn_mfma_scale_f32_32x32x64_f8f6f4(
          a1e, be, acc1, 4, 4, 0, 0x7F7F7F7F, 0, 0x7F7F7F7F);
    }
  };

  STAGE(0, 0);
  STAGE(1, 1);

  int buf = 0;
#pragma unroll 1
  for (int kb = 0; kb < 9; ++kb) {
    if (kb < 8) {
      asm volatile("s_waitcnt vmcnt(5)" ::: "memory");
    } else {
      asm volatile("s_waitcnt vmcnt(0)" ::: "memory");
    }
    __builtin_amdgcn_s_barrier();
    asm volatile("" ::: "memory");
    COMPUTE(buf);
    asm volatile("" ::: "memory");
    __builtin_amdgcn_s_barrier();
    asm volatile("" ::: "memory");
    if (kb < 7) STAGE(kb + 2, buf);
    buf ^= 1;
  }

  int* red = (int*)sB;
  int mx0 = 0, mx1 = 0;
  {
    const int co = n0 + wn * 32 + (lane & 31);
    const int rbase = m0 + wm * 32 + 4 * (lane >> 5);
#pragma unroll
    for (int r = 0; r < 16; ++r) {
      const int m = rbase + (r & 3) + 8 * (r >> 2);
      int v0 = __float2int_rn(acc0[r]);
      int v1 = __float2int_rn(acc1[r]);
      mx0 = max(mx0, v0 < 0 ? -v0 : v0);
      mx1 = max(mx1, v1 < 0 ? -v1 : v1);
      size_t idx = (size_t)m * COUTc + co;
      p0[idx] = (short)v0;
      p1[idx] = (short)v1;
    }
  }
#pragma unroll
  for (int off = 32; off; off >>= 1) {
    mx0 = max(mx0, __shfl_xor(mx0, off));
    mx1 = max(mx1, __shfl_xor(mx1, off));
  }
  if (lane == 0) { red[wid] = mx0; red[wid + 8] = mx1; }
  __syncthreads();
  if (tid == 0) {
    int a = 0, b = 0;
#pragma unroll
    for (int i = 0; i < 8; ++i) { a = max(a, red[i]); b = max(b, red[i + 8]); }
    slot0[bid] = a;
    slot1[bid] = b;
  }
}

__device__ __forceinline__ float compute_val(int a, int b, float sa0, float sa1) {
  float q0 = rintf(__fdiv_rn((float)a, sa0));
  q0 = fminf(31.f, fmaxf(-31.f, q0));
  float q1 = rintf(__fdiv_rn((float)b, sa1));
  q1 = fminf(31.f, fmaxf(-31.f, q1));
  float acc = __fadd_rn(__fmul_rn(q0, sa0), __fmul_rn(__fmul_rn(q1, sa1), 4.0f));
  float pe = (float)(a + 4 * b);
  return __fadd_rn(pe, __fsub_rn(acc, pe));
}

// ============ K4: max|val| partials ============
__global__ __launch_bounds__(256) void k_maxval(char* __restrict__ ws) {
  __shared__ float redf[4];
  const short* p0 = (const short*)(ws + OFF_P0);
  const short* p1 = (const short*)(ws + OFF_P1);
  const int* slot0 = (const int*)(ws + 2048);
  const int* slot1 = (const int*)(ws + 4096);
  float* slot_v = (float*)(ws + 6144);

  const float sa0 = fmaxf(__fdiv_rn((float)wave_max_i(slot0, 392), 31.0f), 1e-12f);
  const float sa1 = fmaxf(__fdiv_rn((float)wave_max_i(slot1, 392), 31.0f), 1e-12f);

  float mv = 0.f;
  const short4* p04 = (const short4*)p0;
  const short4* p14 = (const short4*)p1;
  const int n4 = MD * COUTc / 4;
  for (int i = blockIdx.x * 256 + threadIdx.x; i < n4; i += 512 * 256) {
    short4 a = p04[i], b = p14[i];
    mv = fmaxf(mv, fmaxf(fmaxf(fabsf(compute_val(a.x, b.x, sa0, sa1)),
                               fabsf(compute_val(a.y, b.y, sa0, sa1))),
                         fmaxf(fabsf(compute_val(a.z, b.z, sa0, sa1)),
                               fabsf(compute_val(a.w, b.w, sa0, sa1)))));
  }
#pragma unroll
  for (int off = 32; off; off >>= 1) mv = fmaxf(mv, __shfl_xor(mv, off));
  if ((threadIdx.x & 63) == 0) redf[threadIdx.x >> 6] = mv;
  __syncthreads();
  if (threadIdx.x == 0)
    slot_v[blockIdx.x] = fmaxf(fmaxf(redf[0], redf[1]), fmaxf(redf[2], redf[3]));
}

// ============ K5: requant + bias + transpose to [n][co][l] ============
__global__ __launch_bounds__(256) void k_final(const float* __restrict__ bias,
                                               float* __restrict__ out,
                                               char* __restrict__ ws) {
  __shared__ short t0[64 * 66];
  __shared__ short t1[64 * 66];
  const short* p0 = (const short*)(ws + OFF_P0);
  const short* p1 = (const short*)(ws + OFF_P1);
  const float* slot_a = (const float*)ws;
  const int* slot0 = (const int*)(ws + 2048);
  const int* slot1 = (const int*)(ws + 4096);
  const float* slot_v = (const float*)(ws + 6144);

  const float sx  = fmaxf(__fdiv_rn(wave_max_f(slot_a, 256), 7.0f), 1e-12f);
  const float sa0 = fmaxf(__fdiv_rn((float)wave_max_i(slot0, 392), 31.0f), 1e-12f);
  const float sa1 = fmaxf(__fdiv_rn((float)wave_max_i(slot1, 392), 31.0f), 1e-12f);
  const float so  = fmaxf(__fdiv_rn(__fmul_rn(wave_max_f(slot_v, 512), sx), 127.0f), 1e-12f);

  const int m0 = blockIdx.x * 64, co0 = blockIdx.y * 64;
  const int trow = threadIdx.x >> 3, tseg = threadIdx.x & 7;
#pragma unroll
  for (int p = 0; p < 2; ++p) {
    int ml = p * 32 + trow;
    int4 v0 = *(const int4*)&p0[(size_t)(m0 + ml) * COUTc + co0 + tseg * 8];
    int4 v1 = *(const int4*)&p1[(size_t)(m0 + ml) * COUTc + co0 + tseg * 8];
    const short* s0 = (const short*)&v0;
    const short* s1 = (const short*)&v1;
#pragma unroll
    for (int j = 0; j < 8; ++j) {
      int col = tseg * 8 + j;
      t0[col * 66 + ml] = s0[j];
      t1[col * 66 + ml] = s1[j];
    }
  }
  __syncthreads();
  const int lane16 = threadIdx.x & 15, cg = threadIdx.x >> 4;
#pragma unroll
  for (int p = 0; p < 4; ++p) {
    int col = p * 16 + cg;
    int m4 = lane16 * 4;
    int mg = m0 + m4;
    int nimg = mg / LSP;
    int l = mg - nimg * LSP;
    int co = co0 + col;
    float bv = bias[co];
    float4 o;
    float* op = &o.x;
#pragma unroll
    for (int e = 0; e < 4; ++e) {
      float val = compute_val(t0[col * 66 + m4 + e], t1[col * 66 + m4 + e], sa0, sa1);
      float u = __fmul_rn(val, sx);
      float r = rintf(__fdiv_rn(u, so));
      r = fminf(127.f, fmaxf(-127.f, r));
      op[e] = __fadd_rn(__fmul_rn(r, so), bv);
    }
    *(float4*)&out[((size_t)nimg * COUTc + co) * LSP + l] = o;
  }
}

extern "C" void kernel_launch(void* const* d_in, const int* in_sizes, int n_in,
                              void* d_out, int out_size, void* d_ws, size_t ws_size,
                              hipStream_t stream) {
  const float* x    = (const float*)d_in[0];
  const float* w    = (const float*)d_in[1];
  const float* bias = (const float*)d_in[2];
  float* out = (float*)d_out;
  char* ws = (char*)d_ws;

  k_prep<<<256, 256, 0, stream>>>(x, w, ws);
  k_quant<<<NB * Hc, 1024, 0, stream>>>(x, ws);
  k_gemm<<<392, 512, 0, stream>>>(ws);
  k_maxval<<<512, 256, 0, stream>>>(ws);
  k_final<<<dim3(MD / 64, COUTc / 64), 256, 0, stream>>>(bias, out, ws);
}

// Round 19
// 64.126 us; speedup vs baseline: 1.5066x; 1.0009x over previous
//
#include <hip/hip_runtime.h>
#include <hip/hip_bf16.h>

typedef int   i32x4  __attribute__((ext_vector_type(4)));
typedef int   i32x8  __attribute__((ext_vector_type(8)));
typedef float f32x16 __attribute__((ext_vector_type(16)));

#define GLL16(gp, lp)                                                          \
  __builtin_amdgcn_global_load_lds(                                            \
      (const __attribute__((address_space(1))) void*)(gp),                     \
      (__attribute__((address_space(3))) void*)(lp), 16, 0, 0)

namespace {
constexpr int NB = 4, CINc = 256, Hc = 56, Wc = 56, COUTc = 256;
constexpr int LSP = 56 * 56;           // 3136 output pixels per image
constexpr int MD  = NB * LSP;          // 12544 GEMM rows
constexpr int KT  = 2304;              // 256*9 (K elements)
constexpr int YP = 58, XP = 58;        // padded spatial

constexpr size_t OFF_A0 = 8192;        // slot_a@0, slot0@2048, slot1@4096, slot_v@6144
constexpr size_t SZ_A4  = (size_t)NB * YP * XP * 128;       // 1,722,368
constexpr size_t OFF_A1 = OFF_A0 + SZ_A4;
constexpr size_t OFF_BW = OFF_A1 + SZ_A4;
constexpr size_t SZ_BW4 = (size_t)COUTc * (KT / 2);         // 294,912
constexpr size_t OFF_PP = OFF_BW + SZ_BW4;                  // pint: (p0,p1) packed i32
constexpr size_t SZ_PP  = (size_t)MD * COUTc * 4;           // 12,845,056
} // namespace

__device__ __forceinline__ float wave_max_f(const float* __restrict__ s, int n) {
  float m = 0.f;
  for (int i = (threadIdx.x & 63); i < n; i += 64) m = fmaxf(m, s[i]);
#pragma unroll
  for (int off = 32; off; off >>= 1) m = fmaxf(m, __shfl_xor(m, off));
  return m;
}
__device__ __forceinline__ int wave_max_i(const int* __restrict__ s, int n) {
  int m = 0;
  for (int i = (threadIdx.x & 63); i < n; i += 64) m = max(m, s[i]);
#pragma unroll
  for (int off = 32; off; off >>= 1) m = max(m, __shfl_xor(m, off));
  return m;
}

// ============ K1: absmax(x) partials + binarize/pack W (fp4) ============
__global__ __launch_bounds__(256) void k_prep(const float* __restrict__ x,
                                              const float* __restrict__ w,
                                              char* __restrict__ ws) {
  __shared__ unsigned char sW[KT];     // fp4 codes: +1 -> 0x2, -1 -> 0xA
  __shared__ float redf[4];
  float* slot_a = (float*)ws;
  char* bw4 = ws + OFF_BW;
  const int tid = threadIdx.x, bid = blockIdx.x;
  const int gtid = bid * 256 + tid;

  {
    const float* src = w + (size_t)bid * KT;
    for (int t = tid; t < KT; t += 256)             // t = cin*9 + s
      sW[t] = src[t] >= 0.f ? 0x2u : 0xAu;
    __syncthreads();
    char4* dst4 = (char4*)(bw4 + (size_t)bid * (KT / 2));
    for (int j4 = tid; j4 < KT / 8; j4 += 256) {    // 288 char4 per co
      char4 v; unsigned char* vp = (unsigned char*)&v;
#pragma unroll
      for (int e = 0; e < 4; ++e) {
        int b = j4 * 4 + e;
        int cin = (2 * b) & 255, s = (2 * b) >> 8;
        vp[e] = (unsigned char)(sW[cin * 9 + s] | (sW[(cin + 1) * 9 + s] << 4));
      }
      dst4[j4] = v;
    }
  }
  {
    float mx = 0.f;
    const float4* x4 = (const float4*)x;
    const int n4 = NB * CINc * Hc * Wc / 4;         // 802,816
    for (int i = gtid; i < n4; i += 256 * 256) {
      float4 v = x4[i];
      mx = fmaxf(mx, fmaxf(fmaxf(fabsf(v.x), fabsf(v.y)), fmaxf(fabsf(v.z), fabsf(v.w))));
    }
#pragma unroll
    for (int off = 32; off; off >>= 1) mx = fmaxf(mx, __shfl_xor(mx, off));
    if ((tid & 63) == 0) redf[tid >> 6] = mx;
    __syncthreads();
    if (tid == 0) slot_a[bid] = fmaxf(fmaxf(redf[0], redf[1]), fmaxf(redf[2], redf[3]));
  }
}

// ============ K2: quantize -> fp4-code DAC slices + zero own pad borders ============
__global__ __launch_bounds__(1024) void k_quant(const float* __restrict__ x,
                                                char* __restrict__ ws) {
  __shared__ unsigned char t0[56 * 256];
  __shared__ unsigned char t1[56 * 256];
  const float* slot_a = (const float*)ws;
  char* a0 = ws + OFF_A0;
  char* a1 = ws + OFF_A1;
  const int n = blockIdx.x / Hc, h = blockIdx.x % Hc;
  const float gmax = wave_max_f(slot_a, 256);
  const float sx = fmaxf(__fdiv_rn(gmax, 7.0f), 1e-12f);

  {
    const int tid = threadIdx.x;
    if (tid < 16) {
      int cell = tid >> 3, seg = (tid & 7) * 16;
      int xx = cell ? 57 : 0;
      size_t base = (((size_t)n * YP + (h + 1)) * XP + xx) * 128 + seg;
      *(int4*)&a0[base] = int4{0, 0, 0, 0};
      *(int4*)&a1[base] = int4{0, 0, 0, 0};
    }
    if (h == 0 || h == 55) {
      int yy = (h == 0) ? 0 : 57;
      for (int i = tid; i < 464; i += 1024) {
        size_t base = ((size_t)n * YP + yy) * (size_t)XP * 128 + (size_t)i * 16;
        *(int4*)&a0[base] = int4{0, 0, 0, 0};
        *(int4*)&a1[base] = int4{0, 0, 0, 0};
      }
    }
  }

  const int c = threadIdx.x & 255, wq = threadIdx.x >> 8;
  const float2* src = (const float2*)(x + (((size_t)n * CINc + c) * Hc + h) * Wc + wq * 14);
#pragma unroll
  for (int j = 0; j < 7; ++j) {
    float2 v = src[j];
    float arr[2] = {v.x, v.y};
#pragma unroll
    for (int e = 0; e < 2; ++e) {
      float qf = rintf(__fdiv_rn(arr[e], sx));
      qf = fminf(7.f, fmaxf(-7.f, qf));
      int qi = (int)qf;
      int mag = qi < 0 ? -qi : qi;
      int m0_ = mag & 3, m1_ = mag >> 2;
      // fp4 E2M1 codes: 0->0x0, 1->0x2, 2->0x4, 3->0x5; sign bit 0x8
      int c0 = (m0_ == 3 ? 5 : (m0_ << 1)) | ((qi < 0 && m0_) ? 8 : 0);
      int c1 = (m1_ ? 2 : 0) | ((qi < 0 && m1_) ? 8 : 0);
      int ww = wq * 14 + j * 2 + e;
      t0[ww * 256 + c] = (unsigned char)c0;
      t1[ww * 256 + c] = (unsigned char)c1;
    }
  }
  __syncthreads();
  {
    int idx = threadIdx.x;              // 56 rows x 8 int4-chunks = 448 slots
    if (idx < 448) {
      int wr = idx >> 3, cs = (idx & 7) * 32;
      int4 o0, o1;
      unsigned char* b0 = (unsigned char*)&o0;
      unsigned char* b1 = (unsigned char*)&o1;
#pragma unroll
      for (int b = 0; b < 16; ++b) {
        b0[b] = (unsigned char)(t0[wr * 256 + cs + 2 * b] | (t0[wr * 256 + cs + 2 * b + 1] << 4));
        b1[b] = (unsigned char)(t1[wr * 256 + cs + 2 * b] | (t1[wr * 256 + cs + 2 * b + 1] << 4));
      }
      size_t dst = (((size_t)n * YP + (h + 1)) * XP + (wr + 1)) * 128 + (idx & 7) * 16;
      *(int4*)&a0[dst] = o0;
      *(int4*)&a1[dst] = o1;
    }
  }
}

// ============ K3: dual MX-fp4 GEMM, 128x64 tile, 392 blocks, counted-vmcnt ============
// Output: packed pint[m][co] = (p0 & 0xFFFF) | (p1 << 16) -> 16 coalesced 4B stores/lane.
__global__ __launch_bounds__(512) void k_gemm(char* __restrict__ ws) {
  __shared__ __align__(16) char sA0[2 * 16384];
  __shared__ __align__(16) char sA1[2 * 16384];
  __shared__ __align__(16) char sB[2 * 8192];     // 80 KB -> 2 blocks/CU

  const char* a0cl = ws + OFF_A0;
  const char* a1cl = ws + OFF_A1;
  const char* bw4  = ws + OFF_BW;
  int* pint = (int*)(ws + OFF_PP);
  int* slot0 = (int*)(ws + 2048);
  int* slot1 = (int*)(ws + 4096);

  const int tid = threadIdx.x;
  const int lane = tid & 63, wid = tid >> 6;
  const int wm = wid >> 1, wn = wid & 1;

  const int bid = blockIdx.x;
  const int wg = (bid & 7) * 49 + (bid >> 3);     // 392 = 8*49 exact XCD swizzle
  const int mblk = wg % 98, nblk = wg / 98;
  const int m0 = mblk * 128, n0 = nblk * 64;

  f32x16 acc0 = {};
  f32x16 acc1 = {};

  const int trow = tid >> 3;
  const int cbs = (((tid & 7) << 4) ^ ((trow & 7) << 4));

  int rn[2], roh[2], rww[2];
#pragma unroll
  for (int p = 0; p < 2; ++p) {
    int m = m0 + p * 64 + trow;
    rn[p] = m / LSP; int l = m - rn[p] * LSP;
    roh[p] = l / 56; rww[p] = l - roh[p] * 56;
  }
  const int lbase0 = (wid * 8) * 128;
  const int lbase1 = (64 + wid * 8) * 128;
  const int lbaseB = wid * 8 * 128;

  auto STAGE = [&](int kb, int buf) {
    const int kh = kb / 3, kw = kb - kh * 3;
    {
      size_t ga = (((size_t)rn[0] * YP + (roh[0] + kh)) * XP + (rww[0] + kw)) * 128 + cbs;
      GLL16(a0cl + ga, sA0 + buf * 16384 + lbase0);
      GLL16(a1cl + ga, sA1 + buf * 16384 + lbase0);
    }
    {
      size_t ga = (((size_t)rn[1] * YP + (roh[1] + kh)) * XP + (rww[1] + kw)) * 128 + cbs;
      GLL16(a0cl + ga, sA0 + buf * 16384 + lbase1);
      GLL16(a1cl + ga, sA1 + buf * 16384 + lbase1);
    }
    {
      size_t gb = (size_t)(n0 + trow) * (KT / 2) + kb * 128 + cbs;
      GLL16(bw4 + gb, sB + buf * 8192 + lbaseB);
    }
  };

  const int arow = wm * 32 + (lane & 31);
  const int brow = wn * 32 + (lane & 31);
  const int kh16 = lane >> 5;

  auto COMPUTE = [&](int buf) {
    const char* bA0 = sA0 + buf * 16384 + arow * 128;
    const char* bA1 = sA1 + buf * 16384 + arow * 128;
    const char* bB  = sB + buf * 8192 + brow * 128;
#pragma unroll
    for (int c = 0; c < 4; ++c) {
      const int seg = c * 2 + kh16;
      i32x4 a0v = *(const i32x4*)(bA0 + ((seg ^ (arow & 7)) << 4));
      i32x4 a1v = *(const i32x4*)(bA1 + ((seg ^ (arow & 7)) << 4));
      i32x4 bv  = *(const i32x4*)(bB + ((seg ^ (brow & 7)) << 4));
      i32x8 a0e = {a0v[0], a0v[1], a0v[2], a0v[3], 0, 0, 0, 0};
      i32x8 a1e = {a1v[0], a1v[1], a1v[2], a1v[3], 0, 0, 0, 0};
      i32x8 be  = {bv[0], bv[1], bv[2], bv[3], 0, 0, 0, 0};
      acc0 = __builtin_amdgcn_mfma_scale_f32_32x32x64_f8f6f4(
          a0e, be, acc0, 4, 4, 0, 0x7F7F7F7F, 0, 0x7F7F7F7F);
      acc1 = __builtin_amdgcn_mfma_scale_f32_32x32x64_f8f6f4(
          a1e, be, acc1, 4, 4, 0, 0x7F7F7F7F, 0, 0x7F7F7F7F);
    }
  };

  STAGE(0, 0);
  STAGE(1, 1);

  int buf = 0;
#pragma unroll 1
  for (int kb = 0; kb < 9; ++kb) {
    if (kb < 8) {
      asm volatile("s_waitcnt vmcnt(5)" ::: "memory");
    } else {
      asm volatile("s_waitcnt vmcnt(0)" ::: "memory");
    }
    __builtin_amdgcn_s_barrier();
    asm volatile("" ::: "memory");
    COMPUTE(buf);
    asm volatile("" ::: "memory");
    __builtin_amdgcn_s_barrier();
    asm volatile("" ::: "memory");
    if (kb < 7) STAGE(kb + 2, buf);
    buf ^= 1;
  }

  // epilogue: C/D layout col=lane&31, row=(r&3)+8*(r>>2)+4*(lane>>5); pack+store i32
  int* red = (int*)sB;
  int mx0 = 0, mx1 = 0;
  {
    const int co = n0 + wn * 32 + (lane & 31);
    const int rbase = m0 + wm * 32 + 4 * (lane >> 5);
#pragma unroll
    for (int r = 0; r < 16; ++r) {
      const int m = rbase + (r & 3) + 8 * (r >> 2);
      int v0 = __float2int_rn(acc0[r]);
      int v1 = __float2int_rn(acc1[r]);
      mx0 = max(mx0, v0 < 0 ? -v0 : v0);
      mx1 = max(mx1, v1 < 0 ? -v1 : v1);
      pint[(size_t)m * COUTc + co] = (v0 & 0xFFFF) | (v1 << 16);
    }
  }
#pragma unroll
  for (int off = 32; off; off >>= 1) {
    mx0 = max(mx0, __shfl_xor(mx0, off));
    mx1 = max(mx1, __shfl_xor(mx1, off));
  }
  if (lane == 0) { red[wid] = mx0; red[wid + 8] = mx1; }
  __syncthreads();
  if (tid == 0) {
    int a = 0, b = 0;
#pragma unroll
    for (int i = 0; i < 8; ++i) { a = max(a, red[i]); b = max(b, red[i + 8]); }
    slot0[bid] = a;
    slot1[bid] = b;
  }
}

__device__ __forceinline__ float compute_val(int a, int b, float sa0, float sa1) {
  float q0 = rintf(__fdiv_rn((float)a, sa0));
  q0 = fminf(31.f, fmaxf(-31.f, q0));
  float q1 = rintf(__fdiv_rn((float)b, sa1));
  q1 = fminf(31.f, fmaxf(-31.f, q1));
  float acc = __fadd_rn(__fmul_rn(q0, sa0), __fmul_rn(__fmul_rn(q1, sa1), 4.0f));
  float pe = (float)(a + 4 * b);
  return __fadd_rn(pe, __fsub_rn(acc, pe));
}
__device__ __forceinline__ float val_from_packed(int pv, float sa0, float sa1) {
  return compute_val((int)(short)(pv & 0xFFFF), pv >> 16, sa0, sa1);
}

// ============ K4: max|val| partials (single packed stream) ============
__global__ __launch_bounds__(256) void k_maxval(char* __restrict__ ws) {
  __shared__ float redf[4];
  const int4* pp4 = (const int4*)(ws + OFF_PP);
  const int* slot0 = (const int*)(ws + 2048);
  const int* slot1 = (const int*)(ws + 4096);
  float* slot_v = (float*)(ws + 6144);

  const float sa0 = fmaxf(__fdiv_rn((float)wave_max_i(slot0, 392), 31.0f), 1e-12f);
  const float sa1 = fmaxf(__fdiv_rn((float)wave_max_i(slot1, 392), 31.0f), 1e-12f);

  float mv = 0.f;
  const int n4 = MD * COUTc / 4;                    // 802,816 int4 slots
  for (int i = blockIdx.x * 256 + threadIdx.x; i < n4; i += 512 * 256) {
    int4 v = pp4[i];
    mv = fmaxf(mv, fmaxf(fmaxf(fabsf(val_from_packed(v.x, sa0, sa1)),
                               fabsf(val_from_packed(v.y, sa0, sa1))),
                         fmaxf(fabsf(val_from_packed(v.z, sa0, sa1)),
                               fabsf(val_from_packed(v.w, sa0, sa1)))));
  }
#pragma unroll
  for (int off = 32; off; off >>= 1) mv = fmaxf(mv, __shfl_xor(mv, off));
  if ((threadIdx.x & 63) == 0) redf[threadIdx.x >> 6] = mv;
  __syncthreads();
  if (threadIdx.x == 0)
    slot_v[blockIdx.x] = fmaxf(fmaxf(redf[0], redf[1]), fmaxf(redf[2], redf[3]));
}

// ============ K5: requant + bias + transpose to [n][co][l] ============
__global__ __launch_bounds__(256) void k_final(const float* __restrict__ bias,
                                               float* __restrict__ out,
                                               char* __restrict__ ws) {
  __shared__ int tpk[64 * 66];                      // packed (p0,p1) pairs
  const int* pint = (const int*)(ws + OFF_PP);
  const float* slot_a = (const float*)ws;
  const int* slot0 = (const int*)(ws + 2048);
  const int* slot1 = (const int*)(ws + 4096);
  const float* slot_v = (const float*)(ws + 6144);

  const float sx  = fmaxf(__fdiv_rn(wave_max_f(slot_a, 256), 7.0f), 1e-12f);
  const float sa0 = fmaxf(__fdiv_rn((float)wave_max_i(slot0, 392), 31.0f), 1e-12f);
  const float sa1 = fmaxf(__fdiv_rn((float)wave_max_i(slot1, 392), 31.0f), 1e-12f);
  const float so  = fmaxf(__fdiv_rn(__fmul_rn(wave_max_f(slot_v, 512), sx), 127.0f), 1e-12f);

  const int m0 = blockIdx.x * 64, co0 = blockIdx.y * 64;
  const int trow = threadIdx.x >> 3, tseg = threadIdx.x & 7;
#pragma unroll
  for (int p = 0; p < 2; ++p) {
    int ml = p * 32 + trow;
    const int* row = &pint[(size_t)(m0 + ml) * COUTc + co0 + tseg * 8];
    int4 v0 = *(const int4*)row;
    int4 v1 = *(const int4*)(row + 4);
    const int* s = (const int*)&v0;
#pragma unroll
    for (int j = 0; j < 4; ++j) tpk[(tseg * 8 + j) * 66 + ml] = s[j];
    s = (const int*)&v1;
#pragma unroll
    for (int j = 0; j < 4; ++j) tpk[(tseg * 8 + 4 + j) * 66 + ml] = s[j];
  }
  __syncthreads();
  const int lane16 = threadIdx.x & 15, cg = threadIdx.x >> 4;
#pragma unroll
  for (int p = 0; p < 4; ++p) {
    int col = p * 16 + cg;
    int m4 = lane16 * 4;
    int mg = m0 + m4;
    int nimg = mg / LSP;
    int l = mg - nimg * LSP;
    int co = co0 + col;
    float bv = bias[co];
    float4 o;
    float* op = &o.x;
#pragma unroll
    for (int e = 0; e < 4; ++e) {
      float val = val_from_packed(tpk[col * 66 + m4 + e], sa0, sa1);
      float u = __fmul_rn(val, sx);
      float r = rintf(__fdiv_rn(u, so));
      r = fminf(127.f, fmaxf(-127.f, r));
      op[e] = __fadd_rn(__fmul_rn(r, so), bv);
    }
    *(float4*)&out[((size_t)nimg * COUTc + co) * LSP + l] = o;
  }
}

extern "C" void kernel_launch(void* const* d_in, const int* in_sizes, int n_in,
                              void* d_out, int out_size, void* d_ws, size_t ws_size,
                              hipStream_t stream) {
  const float* x    = (const float*)d_in[0];
  const float* w    = (const float*)d_in[1];
  const float* bias = (const float*)d_in[2];
  float* out = (float*)d_out;
  char* ws = (char*)d_ws;

  k_prep<<<256, 256, 0, stream>>>(x, w, ws);
  k_quant<<<NB * Hc, 1024, 0, stream>>>(x, ws);
  k_gemm<<<392, 512, 0, stream>>>(ws);
  k_maxval<<<512, 256, 0, stream>>>(ws);
  k_final<<<dim3(MD / 64, COUTc / 64), 256, 0, stream>>>(bias, out, ws);
}